// Round 5
// baseline (240.987 us; speedup 1.0000x reference)
//
#include <hip/hip_runtime.h>

#define T_TOK 2048
#define H_DIM 1024
#define I_DIM 2048
#define SHBASE 4096              // T*K expert slots; shared slots follow
#define KN_PANEL (1024 * 2048)   // elements per weight panel (both shapes)

typedef short short8 __attribute__((ext_vector_type(8)));
typedef float floatx4 __attribute__((ext_vector_type(4)));

#define WAITVM(N) asm volatile("s_waitcnt vmcnt(" #N ")" ::: "memory")

__device__ __forceinline__ unsigned short f2bf(float f) {
  unsigned int u = __builtin_bit_cast(unsigned int, f);
  u += 0x7FFFu + ((u >> 16) & 1u);
  return (unsigned short)(u >> 16);
}
__device__ __forceinline__ float bf2f(unsigned short u) {
  return __builtin_bit_cast(float, (unsigned int)u << 16);
}
__device__ __forceinline__ void gl16(const void* g, void* l) {
  __builtin_amdgcn_global_load_lds(
      (const __attribute__((address_space(1))) unsigned int*)g,
      (__attribute__((address_space(3))) unsigned int*)l, 16, 0, 0);
}

// Row-pair bank swizzle. Tile = 128 rows x 32 k (4 octs of 8 bf16) = 512 x 16B chunks.
// chunk(r,o) = (r>>1)*8 + ((o + 4*(r&1)) ^ ((r>>1)&7)).
__device__ __forceinline__ int cidx(int r, int o) {
  int p = r >> 1;
  int s = o + ((r & 1) << 2);
  return p * 8 + (s ^ (p & 7));
}

// ---------------------------------------------------------------- weight conv
// fp32 [K][N] row-major -> bf16 image of 8KB tiles in cidx chunk order.
// Coalesced: row-major float4 reads -> bf16 LDS transpose tile T[128][40]
// (32 k + 8 pad shorts = 80B rows, 16B-aligned) -> b128 readback -> uint4 store.
__device__ __forceinline__ void conv_tile(const float* __restrict__ src,
                                          unsigned short* __restrict__ dst,
                                          int N, int nt, int kt, int t,
                                          unsigned short* __restrict__ T) {
  const float* s0 = src + (size_t)(kt * 32) * N + nt * 128;
#pragma unroll
  for (int p = 0; p < 4; ++p) {
    int r = p * 8 + (t >> 5);
    int c = (t & 31) * 4;
    floatx4 v = *(const floatx4*)(s0 + (size_t)r * N + c);
#pragma unroll
    for (int i = 0; i < 4; ++i) T[(c + i) * 40 + r] = f2bf(v[i]);
  }
  __syncthreads();
#pragma unroll
  for (int half = 0; half < 2; ++half) {
    int q = t + half * 256;
    int p2 = q >> 3, s = (q & 7) ^ (p2 & 7);
    int c = p2 * 2 + (s >> 2), o = s & 3;
    uint4 w = *(const uint4*)&T[c * 40 + o * 8];
    *(uint4*)(dst + (size_t)q * 8) = w;
  }
}

// ---------------------------------------------------------------- prep: conv_up + gate fused
__global__ __launch_bounds__(256) void prep_kernel(
    const float* __restrict__ x, const float* __restrict__ gw,
    const float* __restrict__ w1, const float* __restrict__ w3,
    const float* __restrict__ sw1, const float* __restrict__ sw3,
    unsigned short* __restrict__ img, unsigned short* __restrict__ xb,
    int* __restrict__ cnt, int4* __restrict__ rec, float2* __restrict__ wrec)
{
  __shared__ float red[8][4];
  __shared__ unsigned short T[128 * 40];
  int bid = blockIdx.x;
  int tid = threadIdx.x;
  if (bid < 9216) {                       // conv_up: 18 panels x 512 tiles
    int z = bid >> 9;
    int tile = bid & 511;                 // tile = nt*32 + kt
    const float* src = (z < 8)  ? w1 + (size_t)z * KN_PANEL
                     : (z < 16) ? w3 + (size_t)(z - 8) * KN_PANEL
                     : (z == 16) ? sw1 : sw3;
    unsigned short* dst = img + (size_t)z * KN_PANEL + (size_t)tile * 4096;
    conv_tile(src, dst, I_DIM, tile >> 5, tile & 31, tid, T);
    return;
  }
  // ------- gate
  int t = bid - 9216;
  const float* xr = x + (size_t)t * H_DIM;
  float xv[4];
#pragma unroll
  for (int j = 0; j < 4; ++j) {
    int h = tid + j * 256;
    xv[j] = xr[h];
    xb[(size_t)t * H_DIM + h] = f2bf(xv[j]);
  }
  float p[8];
#pragma unroll
  for (int e = 0; e < 8; ++e) {
    const float* gptr = gw + e * H_DIM;
    float s = 0.f;
#pragma unroll
    for (int j = 0; j < 4; ++j) s += xv[j] * gptr[tid + j * 256];
    p[e] = s;
  }
  int lane = tid & 63, wv = tid >> 6;
#pragma unroll
  for (int e = 0; e < 8; ++e) {
    float s = p[e];
#pragma unroll
    for (int off = 32; off > 0; off >>= 1) s += __shfl_down(s, off);
    if (lane == 0) red[e][wv] = s;
  }
  __syncthreads();
  if (tid == 0) {
    float sc[8], pr[8];
    float m = -1e30f;
#pragma unroll
    for (int e = 0; e < 8; ++e) {
      sc[e] = red[e][0] + red[e][1] + red[e][2] + red[e][3];
      m = fmaxf(m, sc[e]);
    }
    float Z = 0.f;
#pragma unroll
    for (int e = 0; e < 8; ++e) { pr[e] = __expf(sc[e] - m); Z += pr[e]; }
#pragma unroll
    for (int e = 0; e < 8; ++e) pr[e] /= Z;
    int i0 = 0;
#pragma unroll
    for (int e = 1; e < 8; ++e) if (pr[e] > pr[i0]) i0 = e;
    int i1 = (i0 == 0) ? 1 : 0;
#pragma unroll
    for (int e = 0; e < 8; ++e) if (e != i0 && pr[e] > pr[i1]) i1 = e;
    float w0 = pr[i0], w1 = pr[i1];
    float s2 = w0 + w1 + 1e-20f;
    w0 /= s2; w1 /= s2;
    int p0 = atomicAdd(&cnt[i0], 1);
    int p1 = atomicAdd(&cnt[i1], 1);
    rec[t] = make_int4(i0, i1, p0, p1);
    wrec[t] = make_float2(w0, w1);
  }
}

__global__ __launch_bounds__(256) void conv_dn(
    const float* __restrict__ w2, const float* __restrict__ sw2,
    unsigned short* __restrict__ img) {
  __shared__ unsigned short T[128 * 40];
  int z = blockIdx.z;
  const float* src = (z < 8) ? w2 + (size_t)z * KN_PANEL : sw2;
  int tile = blockIdx.x * gridDim.y + blockIdx.y;   // nt*64 + kt
  unsigned short* dst = img + (size_t)z * KN_PANEL + (size_t)tile * 4096;
  conv_tile(src, dst, H_DIM, blockIdx.x, blockIdx.y, threadIdx.x, T);
}

// ---------------------------------------------------------------- scatter
__global__ __launch_bounds__(256) void scatter_kernel(
    const int* __restrict__ cnt, const int4* __restrict__ rec,
    int* __restrict__ tok, int2* __restrict__ slots)
{
  int t = blockIdx.x * 256 + threadIdx.x;
  if (t >= T_TOK) return;
  int bases[8];
  int b = 0;
#pragma unroll
  for (int e = 0; e < 8; ++e) { bases[e] = b; b += cnt[e]; }
  int4 r = rec[t];
  int s0 = bases[r.x] + r.z;
  int s1 = bases[r.y] + r.w;
  tok[s0] = t;
  tok[s1] = t;
  tok[SHBASE + t] = t;
  slots[t] = make_int2(s0, s1);
}

// ---------------------------------------------------------------- up GEMM
// 128r x 128c, BK=32, 8 waves (2Mx4N), w1+w3 fused, triple-buffer depth-2
// counted-vmcnt pipeline, all-DMA staging, swizzled LDS.
__global__ __launch_bounds__(512, 4) void ffn_up(
    const unsigned short* __restrict__ xb,
    const unsigned short* __restrict__ imgUp,
    const int* __restrict__ cnt, const int* __restrict__ tok,
    unsigned short* __restrict__ act)
{
  int z = blockIdx.z;
  int base = 0;
#pragma unroll
  for (int e = 0; e < 8; ++e) if (e < z || z == 8) base += cnt[e];
  int nrows = (z == 8) ? T_TOK : cnt[z];
  int row0 = blockIdx.y * 128;
  if (row0 >= nrows) return;
  int nt = blockIdx.x;
  int p1 = (z < 8) ? z : 16;
  int p3 = (z < 8) ? (8 + z) : 17;

  __shared__ unsigned short A[3][4096];
  __shared__ unsigned short B1[3][4096];
  __shared__ unsigned short B3[3][4096];

  const int tid = threadIdx.x;
  const int lane = tid & 63, wv = tid >> 6;
  const int l16 = lane & 15, g = lane >> 4;
  const int wr = wv >> 2, wc = wv & 3;

  // A staging: chunk q = tid; invert cidx to get (row, oct); source pre-swizzled.
  int qp = tid >> 3, qs = (tid & 7) ^ (qp & 7);
  int ar = qp * 2 + (qs >> 2), ao = qs & 3;
  int grow = row0 + ar;
  if (grow >= nrows) grow = nrows - 1;
  const unsigned short* pA = xb + (size_t)tok[base + grow] * H_DIM + ao * 8;
  const unsigned short* pB1 = imgUp + (size_t)p1 * KN_PANEL + (size_t)nt * 32 * 4096 + tid * 8;
  const unsigned short* pB3 = imgUp + (size_t)p3 * KN_PANEL + (size_t)nt * 32 * 4096 + tid * 8;

  int ach[4], bch[2];
#pragma unroll
  for (int m = 0; m < 4; ++m) ach[m] = cidx(wr * 64 + m * 16 + l16, g) * 8;
#pragma unroll
  for (int n = 0; n < 2; ++n) bch[n] = cidx(wc * 32 + n * 16 + l16, g) * 8;

  floatx4 acc1[4][2], acc3[4][2];
#pragma unroll
  for (int m = 0; m < 4; ++m)
#pragma unroll
    for (int n = 0; n < 2; ++n) { acc1[m][n] = (floatx4)0.f; acc3[m][n] = (floatx4)0.f; }

  auto stage = [&](int buf, int ks) {           // 3 VMEM ops
    gl16(pA + ks * 32, &A[buf][wv * 512]);
    gl16(pB1 + (size_t)ks * 4096, &B1[buf][wv * 512]);
    gl16(pB3 + (size_t)ks * 4096, &B3[buf][wv * 512]);
  };
  auto compute = [&](int buf) {
    short8 af[4];
#pragma unroll
    for (int m = 0; m < 4; ++m) af[m] = *(const short8*)&A[buf][ach[m]];
#pragma unroll
    for (int n = 0; n < 2; ++n) {
      short8 b1 = *(const short8*)&B1[buf][bch[n]];
      short8 b3 = *(const short8*)&B3[buf][bch[n]];
#pragma unroll
      for (int m = 0; m < 4; ++m) {
        acc1[m][n] = __builtin_amdgcn_mfma_f32_16x16x32_bf16(af[m], b1, acc1[m][n], 0, 0, 0);
        acc3[m][n] = __builtin_amdgcn_mfma_f32_16x16x32_bf16(af[m], b3, acc3[m][n], 0, 0, 0);
      }
    }
  };

  const int NT = H_DIM / 32;
  stage(0, 0); stage(1, 1);
  for (int ks = 0; ks < NT - 1; ++ks) {
    int cur = ks % 3;
    WAITVM(3);                       // stage(ks) done; stage(ks+1) still in flight
    __builtin_amdgcn_sched_barrier(0);
    __builtin_amdgcn_s_barrier();
    if (ks + 2 < NT) stage((ks + 2) % 3, ks + 2);
    __builtin_amdgcn_s_setprio(1);
    compute(cur);
    __builtin_amdgcn_s_setprio(0);
    __builtin_amdgcn_sched_barrier(0);
  }
  WAITVM(0);
  __builtin_amdgcn_sched_barrier(0);
  __builtin_amdgcn_s_barrier();
  compute((NT - 1) % 3);

#pragma unroll
  for (int m = 0; m < 4; ++m) {
    int rl = wr * 64 + m * 16 + g * 4;
#pragma unroll
    for (int n = 0; n < 2; ++n) {
      int col = nt * 128 + wc * 32 + n * 16 + l16;
#pragma unroll
      for (int r = 0; r < 4; ++r) {
        int row = rl + r;
        if (row0 + row < nrows) {
          float h1 = acc1[m][n][r], h3 = acc3[m][n][r];
          float a = h1 / (1.0f + __expf(-h1)) * h3;
          act[(size_t)(base + row0 + row) * I_DIM + col] = f2bf(a);
        }
      }
    }
  }
}

// ---------------------------------------------------------------- down GEMM
__global__ __launch_bounds__(512, 4) void ffn_down(
    const unsigned short* __restrict__ act,
    const unsigned short* __restrict__ imgDn,
    const int* __restrict__ cnt, unsigned short* __restrict__ yslot)
{
  int z = blockIdx.z;
  int base = 0;
#pragma unroll
  for (int e = 0; e < 8; ++e) if (e < z || z == 8) base += cnt[e];
  int nrows = (z == 8) ? T_TOK : cnt[z];
  int row0 = blockIdx.y * 128;
  if (row0 >= nrows) return;
  int nt = blockIdx.x;

  __shared__ unsigned short A[3][4096];
  __shared__ unsigned short B[3][4096];

  const int tid = threadIdx.x;
  const int lane = tid & 63, wv = tid >> 6;
  const int l16 = lane & 15, g = lane >> 4;
  const int wr = wv >> 2, wc = wv & 3;

  int qp = tid >> 3, qs = (tid & 7) ^ (qp & 7);
  int ar = qp * 2 + (qs >> 2), ao = qs & 3;
  int grow = row0 + ar;
  if (grow >= nrows) grow = nrows - 1;
  const unsigned short* pA = act + (size_t)(base + grow) * I_DIM + ao * 8;
  const unsigned short* pB = imgDn + (size_t)z * KN_PANEL + (size_t)nt * 64 * 4096 + tid * 8;

  int ach[4], bch[2];
#pragma unroll
  for (int m = 0; m < 4; ++m) ach[m] = cidx(wr * 64 + m * 16 + l16, g) * 8;
#pragma unroll
  for (int n = 0; n < 2; ++n) bch[n] = cidx(wc * 32 + n * 16 + l16, g) * 8;

  floatx4 acc[4][2];
#pragma unroll
  for (int m = 0; m < 4; ++m)
#pragma unroll
    for (int n = 0; n < 2; ++n) acc[m][n] = (floatx4)0.f;

  auto stage = [&](int buf, int ks) {           // 2 VMEM ops
    gl16(pA + ks * 32, &A[buf][wv * 512]);
    gl16(pB + (size_t)ks * 4096, &B[buf][wv * 512]);
  };
  auto compute = [&](int buf) {
    short8 af[4];
#pragma unroll
    for (int m = 0; m < 4; ++m) af[m] = *(const short8*)&A[buf][ach[m]];
#pragma unroll
    for (int n = 0; n < 2; ++n) {
      short8 bfr = *(const short8*)&B[buf][bch[n]];
#pragma unroll
      for (int m = 0; m < 4; ++m)
        acc[m][n] = __builtin_amdgcn_mfma_f32_16x16x32_bf16(af[m], bfr, acc[m][n], 0, 0, 0);
    }
  };

  const int NT = I_DIM / 32;
  stage(0, 0); stage(1, 1);
  for (int ks = 0; ks < NT - 1; ++ks) {
    int cur = ks % 3;
    WAITVM(2);
    __builtin_amdgcn_sched_barrier(0);
    __builtin_amdgcn_s_barrier();
    if (ks + 2 < NT) stage((ks + 2) % 3, ks + 2);
    __builtin_amdgcn_s_setprio(1);
    compute(cur);
    __builtin_amdgcn_s_setprio(0);
    __builtin_amdgcn_sched_barrier(0);
  }
  WAITVM(0);
  __builtin_amdgcn_sched_barrier(0);
  __builtin_amdgcn_s_barrier();
  compute((NT - 1) % 3);

#pragma unroll
  for (int m = 0; m < 4; ++m) {
    int rl = wr * 64 + m * 16 + g * 4;
#pragma unroll
    for (int n = 0; n < 2; ++n) {
      int col = nt * 128 + wc * 32 + n * 16 + l16;
#pragma unroll
      for (int r = 0; r < 4; ++r) {
        int row = rl + r;
        if (row0 + row < nrows)
          yslot[(size_t)(base + row0 + row) * H_DIM + col] = f2bf(acc[m][n][r]);
      }
    }
  }
}

// ---------------------------------------------------------------- combine
__global__ __launch_bounds__(256) void combine_kernel(
    const unsigned short* __restrict__ y, const int2* __restrict__ slots,
    const float2* __restrict__ wrec, float* __restrict__ out)
{
  int t = blockIdx.x;
  int h = threadIdx.x * 4;
  int2 s = slots[t];
  float2 w = wrec[t];
  ushort4 a = *(const ushort4*)&y[(size_t)s.x * H_DIM + h];
  ushort4 b = *(const ushort4*)&y[(size_t)s.y * H_DIM + h];
  ushort4 c = *(const ushort4*)&y[(size_t)(SHBASE + t) * H_DIM + h];
  floatx4 o;
  o[0] = bf2f(a.x) * w.x + bf2f(b.x) * w.y + bf2f(c.x);
  o[1] = bf2f(a.y) * w.x + bf2f(b.y) * w.y + bf2f(c.y);
  o[2] = bf2f(a.z) * w.x + bf2f(b.z) * w.y + bf2f(c.z);
  o[3] = bf2f(a.w) * w.x + bf2f(b.w) * w.y + bf2f(c.w);
  *(floatx4*)&out[(size_t)t * H_DIM + h] = o;
}

// ---------------------------------------------------------------- launch
extern "C" void kernel_launch(void* const* d_in, const int* in_sizes, int n_in,
                              void* d_out, int out_size, void* d_ws, size_t ws_size,
                              hipStream_t stream) {
  const float* x   = (const float*)d_in[0];
  const float* gw  = (const float*)d_in[1];
  const float* w1  = (const float*)d_in[2];
  const float* w2  = (const float*)d_in[3];
  const float* w3  = (const float*)d_in[4];
  const float* sw1 = (const float*)d_in[5];
  const float* sw2 = (const float*)d_in[6];
  const float* sw3 = (const float*)d_in[7];
  float* out = (float*)d_out;

  char* ws = (char*)d_ws;
  int*            cnt   = (int*)ws;                            // 64 B
  int4*           rec   = (int4*)(ws + 1024);                  // 32 KB
  float2*         wrec  = (float2*)(ws + (64 << 10));          // 16 KB
  int*            tok   = (int*)(ws + (128 << 10));            // 24 KB
  int2*           slots = (int2*)(ws + (192 << 10));           // 16 KB
  unsigned short* xb    = (unsigned short*)(ws + (1 << 20));   // 4 MB
  unsigned short* act   = (unsigned short*)(ws + (8ull << 20));   // 24 MB
  unsigned short* yslot = (unsigned short*)(ws + (32ull << 20));  // 12 MB
  unsigned short* img   = (unsigned short*)(ws + (48ull << 20));  // 72 MB (dn aliases)

  hipMemsetAsync(cnt, 0, 64, stream);

  prep_kernel<<<9216 + T_TOK, 256, 0, stream>>>(x, gw, w1, w3, sw1, sw3,
                                                img, xb, cnt, rec, wrec);
  scatter_kernel<<<T_TOK / 256, 256, 0, stream>>>(cnt, rec, tok, slots);
  ffn_up<<<dim3(I_DIM / 128, 16, 9), 512, 0, stream>>>(xb, img, cnt, tok, act);
  conv_dn<<<dim3(H_DIM / 128, I_DIM / 32, 9), 256, 0, stream>>>(w2, sw2, img);
  ffn_down<<<dim3(H_DIM / 128, 16, 9), 512, 0, stream>>>(act, img, cnt, yslot);
  combine_kernel<<<T_TOK, 256, 0, stream>>>(yslot, slots, wrec, out);
}